// Round 9
// baseline (117.166 us; speedup 1.0000x reference)
//
#include <hip/hip_runtime.h>

#define S_LEN 2048
#define HID   1024
#define NHEAD 16
#define NKVH  4
#define HDIM  64
#define QKSTR 1280   // qkv buffer row stride: Q(1024) + K(256); V goes to vT transposed

typedef __bf16 bf16x8 __attribute__((ext_vector_type(8)));
typedef __bf16 bf16x4 __attribute__((ext_vector_type(4)));
typedef float  f32x4  __attribute__((ext_vector_type(4)));
typedef short  s16x4  __attribute__((ext_vector_type(4)));

// scale = (1/sqrt(1024)) * log2(e): fold softmax scale + base-2 conversion into Q
#define QSCALE 0.04508422f

__device__ __forceinline__ unsigned short f2bf(float f) {
    unsigned u = __builtin_bit_cast(unsigned, f);
    u = u + 0x7FFFu + ((u >> 16) & 1u);   // round-to-nearest-even
    return (unsigned short)(u >> 16);
}

__device__ __forceinline__ bf16x8 cvt8(float4 a, float4 b) {   // RNE, == f2bf bits
    bf16x8 r;
    r[0] = (__bf16)a.x; r[1] = (__bf16)a.y; r[2] = (__bf16)a.z; r[3] = (__bf16)a.w;
    r[4] = (__bf16)b.x; r[5] = (__bf16)b.y; r[6] = (__bf16)b.z; r[7] = (__bf16)b.w;
    return r;
}

// 16x16x16 bf16 MFMA (K=16): B-layout k = quad*4+j matches the S^T output
// granularity exactly -> softmax feeds PV with zero cross-lane movement.
__device__ __forceinline__ f32x4 mfma_16x16x16_bf16(s16x4 a, s16x4 b, f32x4 c) {
#if __has_builtin(__builtin_amdgcn_mfma_f32_16x16x16bf16_1k)
    return __builtin_amdgcn_mfma_f32_16x16x16bf16_1k(a, b, c, 0, 0, 0);
#else
    f32x4 d = c;
    asm volatile("s_nop 1\n\tv_mfma_f32_16x16x16_bf16 %0, %1, %2, %0\n\ts_nop 3"
                 : "+v"(d) : "v"(a), "v"(b));
    return d;
#endif
}

// ---------------- QKV projection, fused fp32->bf16 conversion ----------------
// R9: cvt_all is GONE. The x/W bf16 copies existed only to feed this kernel;
// now the tiles are reg-staged directly from fp32 inputs: load float4 pairs
// from the SAME pre-swizzled source columns the old global_load_lds used,
// RNE-convert in-register, ds_write_b128 to the SAME linear LDS destination
// (dest col = (l&7)*8 holds source col ((l&7)^srow)*8 — byte-identical
// layout, MFMA read path untouched). Removes a kernel + launch gap + 21MB
// of bf16 round-trip traffic. Schedule: write(cur) -> barrier -> load(i+1)
// (flies during compute) -> compute(cur). Race-free as before (write of
// buf^1 at i+1 is separated from its last readers by barrier(i)).
__global__ __launch_bounds__(256, 2) void proj_gemm(
    const float* __restrict__ x,  const float* __restrict__ wq,
    const float* __restrict__ wk, const float* __restrict__ wv,
    unsigned short* __restrict__ qkv,
    unsigned short* __restrict__ vT)
{
    __shared__ unsigned short At[2][64 * 64];
    __shared__ unsigned short Bt[2][96 * 64];
    const int tid = threadIdx.x;
    const int w = tid >> 6, l = tid & 63;
    const int quad = l >> 4, lane16 = l & 15;
    const int m0 = blockIdx.y * 64, n0 = blockIdx.x * 96;
    const int wm = (w & 1) * 32, wn = (w >> 1) * 48;

    const int srow = l >> 3;
    const int scol = ((l & 7) ^ srow) * 8;   // swizzled global col group
    const int dcol = (l & 7) * 8;            // linear LDS dest col group

    f32x4 acc[2][3] = {};
    float4 arA[2][2], arB[3][2];

    #define PLOAD(KT)                                                                   \
        do {                                                                            \
            _Pragma("unroll")                                                           \
            for (int c = 0; c < 2; ++c) {                                               \
                const float* ga = x + (long)(m0 + w * 16 + c * 8 + srow) * HID          \
                                    + (KT) + scol;                                      \
                arA[c][0] = ((const float4*)ga)[0];                                     \
                arA[c][1] = ((const float4*)ga)[1];                                     \
            }                                                                           \
            _Pragma("unroll")                                                           \
            for (int c = 0; c < 3; ++c) {                                               \
                const int row = n0 + w * 24 + c * 8 + srow;                             \
                const float* gb = (row < 1024) ? wq + (long)row * HID                   \
                                : (row < 1280) ? wk + (long)(row - 1024) * HID          \
                                               : wv + (long)(row - 1280) * HID;         \
                gb += (KT) + scol;                                                      \
                arB[c][0] = ((const float4*)gb)[0];                                     \
                arB[c][1] = ((const float4*)gb)[1];                                     \
            }                                                                           \
        } while (0)

    #define PWRITE(BUF)                                                                 \
        do {                                                                            \
            _Pragma("unroll")                                                           \
            for (int c = 0; c < 2; ++c)                                                 \
                *(bf16x8*)&At[BUF][(w * 16 + c * 8 + srow) * 64 + dcol] =               \
                    cvt8(arA[c][0], arA[c][1]);                                         \
            _Pragma("unroll")                                                           \
            for (int c = 0; c < 3; ++c)                                                 \
                *(bf16x8*)&Bt[BUF][(w * 24 + c * 8 + srow) * 64 + dcol] =               \
                    cvt8(arB[c][0], arB[c][1]);                                         \
        } while (0)

    PLOAD(0);

    for (int i = 0; i < 16; ++i) {
        const int cur = i & 1;
        PWRITE(cur);                    // waits on loads (had a full phase to fly)
        __syncthreads();
        if (i + 1 < 16) PLOAD((i + 1) * 64);   // issue after barrier; flies below

        #pragma unroll
        for (int ks = 0; ks < 2; ++ks) {
            const int swz = ((ks * 4 + quad) ^ (lane16 & 7)) * 8;
            bf16x8 a[2], b[3];
            #pragma unroll
            for (int mi = 0; mi < 2; ++mi)
                a[mi] = *(const bf16x8*)&At[cur][(wm + mi * 16 + lane16) * 64 + swz];
            #pragma unroll
            for (int ni = 0; ni < 3; ++ni)
                b[ni] = *(const bf16x8*)&Bt[cur][(wn + ni * 16 + lane16) * 64 + swz];
            #pragma unroll
            for (int mi = 0; mi < 2; ++mi)
                #pragma unroll
                for (int ni = 0; ni < 3; ++ni)
                    acc[mi][ni] = __builtin_amdgcn_mfma_f32_16x16x32_bf16(a[mi], b[ni], acc[mi][ni], 0, 0, 0);
        }
    }
    #undef PLOAD
    #undef PWRITE

    #pragma unroll
    for (int mi = 0; mi < 2; ++mi) {
        const int row = m0 + wm + mi * 16 + quad * 4;
        #pragma unroll
        for (int ni = 0; ni < 3; ++ni) {
            const int col = n0 + wn + ni * 16 + lane16;
            #pragma unroll
            for (int r = 0; r < 4; ++r) {
                const float v = acc[mi][ni][r];
                if (col < 1024)
                    qkv[(long)(row + r) * QKSTR + col] = f2bf(v * QSCALE);
                else if (col < 1280)
                    qkv[(long)(row + r) * QKSTR + col] = f2bf(v);
                else
                    vT[(long)(col - 1280) * S_LEN + (row + r)] = f2bf(v);
            }
        }
    }
}

// ---------------- flash attention (MFMA), causal, GQA rep=4 ----------------
// R9: TWO KV-tiles per barrier epoch, 4 LDS buffers (73.7KB, 2 blocks/CU).
// Halves the barrier count (16.5 -> 8.7 per block) and doubles the compute
// per sync point — attacking the per-epoch serialization floor that left
// R2/R4/R6/R8 all at the same time. Race-freedom: epoch j writes buffer pair
// (j&1)*2, which was last READ at epoch j-1 and is separated from those reads
// by barrier(j) — the same argument as the proven 2-buffer scheme. Core
// compute per tile is the verified R6 16x16x16 path (in-register P).
#define KSTR 72   // LDS row stride (ushorts): multiple of 8 -> 16B-aligned b128
__global__ __launch_bounds__(256, 2) void attn(
    const unsigned short* __restrict__ qkv,
    const unsigned short* __restrict__ vT,
    float* __restrict__ out)
{
    __shared__ unsigned short Kt[4][64 * KSTR];     // K tiles  [kv][d]
    __shared__ unsigned short Vt[4][64 * KSTR];     // V^T tiles [d][kv]

    const int tid = threadIdx.x;
    const int w = tid >> 6, l = tid & 63;
    const int quad = l >> 4, lane16 = l & 15;
    const int bx = blockIdx.x, by = blockIdx.y;
    const int qt = (by & 8) ? (31 - bx) : bx;       // balanced pairing remap
    const int h  = by;
    const int kh = h >> 2;
    const int qcol = h * 64;
    const int kcol = 1024 + kh * 64;

    // Q fragments (B-layout: n=lane16, k=quad*8+j), Q pre-scaled by proj_gemm
    const long qrow = (long)(qt * 64 + w * 16 + lane16);
    bf16x8 qa0 = *(const bf16x8*)&qkv[qrow * QKSTR + qcol + quad * 8];
    bf16x8 qa1 = *(const bf16x8*)&qkv[qrow * QKSTR + qcol + 32 + quad * 8];

    f32x4 oT[4] = {};                // O^T: oT[dt][r] = O[q=lane16][d=dt*16+quad*4+r]
    float rsum[4] = {0.f, 0.f, 0.f, 0.f};

    // staging coords: 256 thr x 16 ushorts cover each 64x64 tile
    const int sr = tid >> 2, ss = tid & 3;
    const long vrow = (long)(kh * 64 + sr) * S_LEN;

    const int nt = qt + 1;                          // number of KV tiles

    // prefetch registers: slot 0 = even tile, slot 1 = odd tile
    bf16x8 kr00, kr01, vr00, vr01;                  // slot 0
    bf16x8 kr10, kr11, vr10, vr11;                  // slot 1

    #define LOADSLOT0(T)                                                        \
        do {                                                                    \
            const long gk = (long)((T) * 64 + sr) * QKSTR + kcol + ss * 16;     \
            kr00 = *(const bf16x8*)&qkv[gk];                                    \
            kr01 = *(const bf16x8*)&qkv[gk + 8];                                \
            const long gv = vrow + (T) * 64 + ss * 16;                          \
            vr00 = *(const bf16x8*)&vT[gv];                                     \
            vr01 = *(const bf16x8*)&vT[gv + 8];                                 \
        } while (0)
    #define LOADSLOT1(T)                                                        \
        do {                                                                    \
            const long gk = (long)((T) * 64 + sr) * QKSTR + kcol + ss * 16;     \
            kr10 = *(const bf16x8*)&qkv[gk];                                    \
            kr11 = *(const bf16x8*)&qkv[gk + 8];                                \
            const long gv = vrow + (T) * 64 + ss * 16;                          \
            vr10 = *(const bf16x8*)&vT[gv];                                     \
            vr11 = *(const bf16x8*)&vT[gv + 8];                                 \
        } while (0)

    LOADSLOT0(0);
    if (nt > 1) LOADSLOT1(1);

    // per-tile compute on buffer buf (verified R6 core)
    auto compute = [&](int buf, int tile) {
        f32x4 sacc[4] = {};
        __builtin_amdgcn_s_setprio(1);
        #pragma unroll
        for (int t = 0; t < 4; ++t) {
            bf16x8 kb0 = *(const bf16x8*)&Kt[buf][(t * 16 + lane16) * KSTR + quad * 8];
            bf16x8 kb1 = *(const bf16x8*)&Kt[buf][(t * 16 + lane16) * KSTR + 32 + quad * 8];
            sacc[t] = __builtin_amdgcn_mfma_f32_16x16x32_bf16(kb0, qa0, sacc[t], 0, 0, 0);
            sacc[t] = __builtin_amdgcn_mfma_f32_16x16x32_bf16(kb1, qa1, sacc[t], 0, 0, 0);
        }
        __builtin_amdgcn_s_setprio(0);

        if (tile == qt) {                 // causal mask on diagonal tile
            #pragma unroll
            for (int t = 0; t < 4; ++t) {
                const int kvw = t * 16 + quad * 4;
                #pragma unroll
                for (int r = 0; r < 4; ++r)
                    if (kvw + r > w * 16 + lane16) sacc[t][r] = -3.0e38f;
            }
        }

        s16x4 pfrag[4];
        #pragma unroll
        for (int t = 0; t < 4; ++t) {
            const float p0 = __builtin_amdgcn_exp2f(sacc[t][0]);
            const float p1 = __builtin_amdgcn_exp2f(sacc[t][1]);
            const float p2 = __builtin_amdgcn_exp2f(sacc[t][2]);
            const float p3 = __builtin_amdgcn_exp2f(sacc[t][3]);
            rsum[t] += (p0 + p1) + (p2 + p3);
            bf16x4 pk;
            pk[0] = (__bf16)p0; pk[1] = (__bf16)p1;
            pk[2] = (__bf16)p2; pk[3] = (__bf16)p3;
            pfrag[t] = __builtin_bit_cast(s16x4, pk);
        }

        __builtin_amdgcn_s_setprio(1);
        #pragma unroll
        for (int dt = 0; dt < 4; ++dt)
            #pragma unroll
            for (int t = 0; t < 4; ++t) {
                bf16x4 va = *(const bf16x4*)&Vt[buf][(dt * 16 + lane16) * KSTR + t * 16 + quad * 4];
                oT[dt] = mfma_16x16x16_bf16(__builtin_bit_cast(s16x4, va), pfrag[t], oT[dt]);
            }
        __builtin_amdgcn_s_setprio(0);
    };

    for (int j = 0; 2 * j < nt; ++j) {
        const int t0 = 2 * j, t1 = 2 * j + 1;
        const bool has1 = (t1 < nt);
        const int p = (j & 1) << 1;               // buffer pair base: 0 or 2

        // store prefetched tiles into this epoch's buffer pair
        *(bf16x8*)&Kt[p][sr * KSTR + ss * 16]     = kr00;
        *(bf16x8*)&Kt[p][sr * KSTR + ss * 16 + 8] = kr01;
        *(bf16x8*)&Vt[p][sr * KSTR + ss * 16]     = vr00;
        *(bf16x8*)&Vt[p][sr * KSTR + ss * 16 + 8] = vr01;
        if (has1) {
            *(bf16x8*)&Kt[p + 1][sr * KSTR + ss * 16]     = kr10;
            *(bf16x8*)&Kt[p + 1][sr * KSTR + ss * 16 + 8] = kr11;
            *(bf16x8*)&Vt[p + 1][sr * KSTR + ss * 16]     = vr10;
            *(bf16x8*)&Vt[p + 1][sr * KSTR + ss * 16 + 8] = vr11;
        }
        __syncthreads();                          // ONE barrier per 2 tiles

        // prefetch next epoch's tiles (fly during the compute below)
        if (t0 + 2 < nt) LOADSLOT0(t0 + 2);
        if (t1 + 2 < nt) LOADSLOT1(t1 + 2);

        compute(p, t0);
        if (has1) compute(p + 1, t1);
    }
    #undef LOADSLOT0
    #undef LOADSLOT1

    // rowsum total for q = lane16 (lane-local for O^T): reduce across quads
    float total = (rsum[0] + rsum[1]) + (rsum[2] + rsum[3]);
    total += __shfl_xor(total, 16);
    total += __shfl_xor(total, 32);
    const float invt = 1.0f / total;

    const long orow_q = (long)(qt * 64 + w * 16 + lane16);
    #pragma unroll
    for (int dt = 0; dt < 4; ++dt) {
        const int col = h * 64 + dt * 16 + quad * 4;
        #pragma unroll
        for (int r = 0; r < 4; ++r)
            out[orow_q * (NHEAD * HDIM) + col + r] = oT[dt][r] * invt;
    }
}

extern "C" void kernel_launch(void* const* d_in, const int* in_sizes, int n_in,
                              void* d_out, int out_size, void* d_ws, size_t ws_size,
                              hipStream_t stream) {
    const float* x  = (const float*)d_in[0];
    const float* wq = (const float*)d_in[1];
    const float* wk = (const float*)d_in[2];
    const float* wv = (const float*)d_in[3];
    float* out = (float*)d_out;

    unsigned short* qkv = (unsigned short*)d_ws;                 // 2048*1280 (Q+K)
    unsigned short* vT  = qkv + (size_t)S_LEN * QKSTR;           // 256*2048  (V^T)

    proj_gemm<<<dim3(16, 32), dim3(256), 0, stream>>>(x, wq, wk, wv, qkv, vT);
    attn<<<dim3(32, 16), dim3(256), 0, stream>>>(qkv, vT, out);
}

// Round 10
// 114.364 us; speedup vs baseline: 1.0245x; 1.0245x over previous
//
#include <hip/hip_runtime.h>

#define S_LEN 2048
#define HID   1024
#define NHEAD 16
#define NKVH  4
#define HDIM  64
#define QKSTR 1280   // qkv buffer row stride: Q(1024) + K(256); V goes to vT transposed

typedef __bf16 bf16x8 __attribute__((ext_vector_type(8)));
typedef __bf16 bf16x4 __attribute__((ext_vector_type(4)));
typedef float  f32x4  __attribute__((ext_vector_type(4)));
typedef short  s16x4  __attribute__((ext_vector_type(4)));

// scale = (1/sqrt(1024)) * log2(e): fold softmax scale + base-2 conversion into Q
#define QSCALE 0.04508422f

__device__ __forceinline__ unsigned short f2bf(float f) {
    unsigned u = __builtin_bit_cast(unsigned, f);
    u = u + 0x7FFFu + ((u >> 16) & 1u);   // round-to-nearest-even
    return (unsigned short)(u >> 16);
}

__device__ __forceinline__ bf16x8 cvt8(float4 a, float4 b) {   // RNE, == f2bf bits
    bf16x8 r;
    r[0] = (__bf16)a.x; r[1] = (__bf16)a.y; r[2] = (__bf16)a.z; r[3] = (__bf16)a.w;
    r[4] = (__bf16)b.x; r[5] = (__bf16)b.y; r[6] = (__bf16)b.z; r[7] = (__bf16)b.w;
    return r;
}

// 16x16x16 bf16 MFMA (K=16): B-layout k = quad*4+j matches the S^T output
// granularity exactly -> softmax feeds PV with zero cross-lane movement.
__device__ __forceinline__ f32x4 mfma_16x16x16_bf16(s16x4 a, s16x4 b, f32x4 c) {
#if __has_builtin(__builtin_amdgcn_mfma_f32_16x16x16bf16_1k)
    return __builtin_amdgcn_mfma_f32_16x16x16bf16_1k(a, b, c, 0, 0, 0);
#else
    f32x4 d = c;
    asm volatile("s_nop 1\n\tv_mfma_f32_16x16x16_bf16 %0, %1, %2, %0\n\ts_nop 3"
                 : "+v"(d) : "v"(a), "v"(b));
    return d;
#endif
}

// ---------------- QKV projection, fused fp32->bf16 conversion (R9, passed) ----------------
__global__ __launch_bounds__(256, 2) void proj_gemm(
    const float* __restrict__ x,  const float* __restrict__ wq,
    const float* __restrict__ wk, const float* __restrict__ wv,
    unsigned short* __restrict__ qkv,
    unsigned short* __restrict__ vT)
{
    __shared__ unsigned short At[2][64 * 64];
    __shared__ unsigned short Bt[2][96 * 64];
    const int tid = threadIdx.x;
    const int w = tid >> 6, l = tid & 63;
    const int quad = l >> 4, lane16 = l & 15;
    const int m0 = blockIdx.y * 64, n0 = blockIdx.x * 96;
    const int wm = (w & 1) * 32, wn = (w >> 1) * 48;

    const int srow = l >> 3;
    const int scol = ((l & 7) ^ srow) * 8;   // swizzled global col group
    const int dcol = (l & 7) * 8;            // linear LDS dest col group

    f32x4 acc[2][3] = {};
    float4 arA[2][2], arB[3][2];

    #define PLOAD(KT)                                                                   \
        do {                                                                            \
            _Pragma("unroll")                                                           \
            for (int c = 0; c < 2; ++c) {                                               \
                const float* ga = x + (long)(m0 + w * 16 + c * 8 + srow) * HID          \
                                    + (KT) + scol;                                      \
                arA[c][0] = ((const float4*)ga)[0];                                     \
                arA[c][1] = ((const float4*)ga)[1];                                     \
            }                                                                           \
            _Pragma("unroll")                                                           \
            for (int c = 0; c < 3; ++c) {                                               \
                const int row = n0 + w * 24 + c * 8 + srow;                             \
                const float* gb = (row < 1024) ? wq + (long)row * HID                   \
                                : (row < 1280) ? wk + (long)(row - 1024) * HID          \
                                               : wv + (long)(row - 1280) * HID;         \
                gb += (KT) + scol;                                                      \
                arB[c][0] = ((const float4*)gb)[0];                                     \
                arB[c][1] = ((const float4*)gb)[1];                                     \
            }                                                                           \
        } while (0)

    #define PWRITE(BUF)                                                                 \
        do {                                                                            \
            _Pragma("unroll")                                                           \
            for (int c = 0; c < 2; ++c)                                                 \
                *(bf16x8*)&At[BUF][(w * 16 + c * 8 + srow) * 64 + dcol] =               \
                    cvt8(arA[c][0], arA[c][1]);                                         \
            _Pragma("unroll")                                                           \
            for (int c = 0; c < 3; ++c)                                                 \
                *(bf16x8*)&Bt[BUF][(w * 24 + c * 8 + srow) * 64 + dcol] =               \
                    cvt8(arB[c][0], arB[c][1]);                                         \
        } while (0)

    PLOAD(0);

    for (int i = 0; i < 16; ++i) {
        const int cur = i & 1;
        PWRITE(cur);                    // waits on loads (had a full phase to fly)
        __syncthreads();
        if (i + 1 < 16) PLOAD((i + 1) * 64);   // issue after barrier; flies below

        #pragma unroll
        for (int ks = 0; ks < 2; ++ks) {
            const int swz = ((ks * 4 + quad) ^ (lane16 & 7)) * 8;
            bf16x8 a[2], b[3];
            #pragma unroll
            for (int mi = 0; mi < 2; ++mi)
                a[mi] = *(const bf16x8*)&At[cur][(wm + mi * 16 + lane16) * 64 + swz];
            #pragma unroll
            for (int ni = 0; ni < 3; ++ni)
                b[ni] = *(const bf16x8*)&Bt[cur][(wn + ni * 16 + lane16) * 64 + swz];
            #pragma unroll
            for (int mi = 0; mi < 2; ++mi)
                #pragma unroll
                for (int ni = 0; ni < 3; ++ni)
                    acc[mi][ni] = __builtin_amdgcn_mfma_f32_16x16x32_bf16(a[mi], b[ni], acc[mi][ni], 0, 0, 0);
        }
    }
    #undef PLOAD
    #undef PWRITE

    #pragma unroll
    for (int mi = 0; mi < 2; ++mi) {
        const int row = m0 + wm + mi * 16 + quad * 4;
        #pragma unroll
        for (int ni = 0; ni < 3; ++ni) {
            const int col = n0 + wn + ni * 16 + lane16;
            #pragma unroll
            for (int r = 0; r < 4; ++r) {
                const float v = acc[mi][ni][r];
                if (col < 1024)
                    qkv[(long)(row + r) * QKSTR + col] = f2bf(v * QSCALE);
                else if (col < 1280)
                    qkv[(long)(row + r) * QKSTR + col] = f2bf(v);
                else
                    vT[(long)(col - 1280) * S_LEN + (row + r)] = f2bf(v);
            }
        }
    }
}

// ---------------- flash attention, KV-SPLIT (flash-decoding), causal, GQA ----------------
// R10: grid (32 qt, 16 h, 2 seg) = 1024 blocks -> 4 blocks/CU, 16 waves/CU
// (was 8), 4 independent barrier domains. Attacks the measured stall regime
// (R3 profile: MfmaUtil 5%, VALUBusy 7.6% — latency-bound, TLP-starved).
// Each block computes a PARTIAL O and rsum over its KV segment; because the
// softmax is the no-max exp2 form, partials combine EXACTLY:
// O = (O0+O1) / (r0+r1) — no rescale. Combine is a small BW-bound kernel.
// Tile-epochs total unchanged (each tile staged once). Core per tile is the
// verified R6/R8 path (in-register P via 16x16x16 PV).
#define KSTR 72   // LDS row stride (ushorts): multiple of 8 -> 16B-aligned b128
__global__ __launch_bounds__(256, 4) void attn(
    const unsigned short* __restrict__ qkv,
    const unsigned short* __restrict__ vT,
    float* __restrict__ opart,       // [2][2048][1024] f32
    float* __restrict__ rpart)       // [2][16][2048]  f32
{
    __shared__ unsigned short Kt[2][64 * KSTR];     // K tile  [kv][d]
    __shared__ unsigned short Vt[2][64 * KSTR];     // V^T tile [d][kv]

    const int tid = threadIdx.x;
    const int w = tid >> 6, l = tid & 63;
    const int quad = l >> 4, lane16 = l & 15;
    const int bx = blockIdx.x, by = blockIdx.y, bz = blockIdx.z;
    const int qt = (by & 8) ? (31 - bx) : bx;       // balanced pairing remap
    const int h  = by;
    const int kh = h >> 2;
    const int qcol = h * 64;
    const int kcol = 1024 + kh * 64;

    const int nt  = qt + 1;                         // total KV tiles for this qt
    const int h1  = (nt + 1) >> 1;                  // split point
    const int tlo = bz ? h1 : 0;
    const int thi = bz ? nt : h1;

    // Q fragments (B-layout: n=lane16, k=quad*8+j), Q pre-scaled by proj_gemm
    const long qrow = (long)(qt * 64 + w * 16 + lane16);
    bf16x8 qa0 = *(const bf16x8*)&qkv[qrow * QKSTR + qcol + quad * 8];
    bf16x8 qa1 = *(const bf16x8*)&qkv[qrow * QKSTR + qcol + 32 + quad * 8];

    f32x4 oT[4] = {};                // O^T: oT[dt][r] = O[q=lane16][d=dt*16+quad*4+r]
    float rsum[4] = {0.f, 0.f, 0.f, 0.f};

    // staging coords: 256 thr x 16 ushorts cover each 64x64 tile
    const int sr = tid >> 2, ss = tid & 3;
    const long vrow = (long)(kh * 64 + sr) * S_LEN;

    bf16x8 kr0, kr1, vr0, vr1;
    if (tlo < thi) {                                // prologue: prefetch tile tlo
        const long gk = (long)(tlo * 64 + sr) * QKSTR + kcol + ss * 16;
        kr0 = *(const bf16x8*)&qkv[gk];
        kr1 = *(const bf16x8*)&qkv[gk + 8];
        const long gv = vrow + tlo * 64 + ss * 16;
        vr0 = *(const bf16x8*)&vT[gv];
        vr1 = *(const bf16x8*)&vT[gv + 8];
    }

    for (int kt = tlo; kt < thi; ++kt) {
        const int cur = kt & 1;
        // (A) store prefetched tile into buf[cur]
        *(bf16x8*)&Kt[cur][sr * KSTR + ss * 16]     = kr0;
        *(bf16x8*)&Kt[cur][sr * KSTR + ss * 16 + 8] = kr1;
        *(bf16x8*)&Vt[cur][sr * KSTR + ss * 16]     = vr0;
        *(bf16x8*)&Vt[cur][sr * KSTR + ss * 16 + 8] = vr1;

        __syncthreads();                      // (B) staging[cur] visible

        // issue kt+1 prefetch after the barrier (flies during compute below)
        if (kt + 1 < thi) {
            const long gk = (long)((kt + 1) * 64 + sr) * QKSTR + kcol + ss * 16;
            kr0 = *(const bf16x8*)&qkv[gk];
            kr1 = *(const bf16x8*)&qkv[gk + 8];
            const long gv = vrow + (kt + 1) * 64 + ss * 16;
            vr0 = *(const bf16x8*)&vT[gv];
            vr1 = *(const bf16x8*)&vT[gv + 8];
        }

        // S^T = K Q^T  (64 kv x 16 q-rows); C: row=kv=t*16+quad*4+r, col=lane16
        f32x4 sacc[4] = {};
        __builtin_amdgcn_s_setprio(1);
        #pragma unroll
        for (int t = 0; t < 4; ++t) {
            bf16x8 kb0 = *(const bf16x8*)&Kt[cur][(t * 16 + lane16) * KSTR + quad * 8];
            bf16x8 kb1 = *(const bf16x8*)&Kt[cur][(t * 16 + lane16) * KSTR + 32 + quad * 8];
            sacc[t] = __builtin_amdgcn_mfma_f32_16x16x32_bf16(kb0, qa0, sacc[t], 0, 0, 0);
            sacc[t] = __builtin_amdgcn_mfma_f32_16x16x32_bf16(kb1, qa1, sacc[t], 0, 0, 0);
        }
        __builtin_amdgcn_s_setprio(0);

        // causal mask on diagonal tile: kv > qrow  (both local to this 64-block)
        if (kt == qt) {
            #pragma unroll
            for (int t = 0; t < 4; ++t) {
                const int kvw = t * 16 + quad * 4;
                #pragma unroll
                for (int r = 0; r < 4; ++r)
                    if (kvw + r > w * 16 + lane16) sacc[t][r] = -3.0e38f;
            }
        }

        // softmax: p = exp2(s); lane's 4 values per t ARE the 16x16x16 B-frag
        s16x4 pfrag[4];
        #pragma unroll
        for (int t = 0; t < 4; ++t) {
            const float p0 = __builtin_amdgcn_exp2f(sacc[t][0]);
            const float p1 = __builtin_amdgcn_exp2f(sacc[t][1]);
            const float p2 = __builtin_amdgcn_exp2f(sacc[t][2]);
            const float p3 = __builtin_amdgcn_exp2f(sacc[t][3]);
            rsum[t] += (p0 + p1) + (p2 + p3);
            bf16x4 pk;
            pk[0] = (__bf16)p0; pk[1] = (__bf16)p1;
            pk[2] = (__bf16)p2; pk[3] = (__bf16)p3;
            pfrag[t] = __builtin_bit_cast(s16x4, pk);
        }

        // O^T += V^T P^T  (A = V^T 4 contiguous bf16, b64 read)
        __builtin_amdgcn_s_setprio(1);
        #pragma unroll
        for (int dt = 0; dt < 4; ++dt)
            #pragma unroll
            for (int t = 0; t < 4; ++t) {
                bf16x4 va = *(const bf16x4*)&Vt[cur][(dt * 16 + lane16) * KSTR + t * 16 + quad * 4];
                oT[dt] = mfma_16x16x16_bf16(__builtin_bit_cast(s16x4, va), pfrag[t], oT[dt]);
            }
        __builtin_amdgcn_s_setprio(0);
    }

    // partial rowsum for q = lane16 (all lanes hold their row's total copy)
    float total = (rsum[0] + rsum[1]) + (rsum[2] + rsum[3]);
    total += __shfl_xor(total, 16);
    total += __shfl_xor(total, 32);

    // write partial O (UNNORMALIZED) + partial rsum; zero-work blocks write 0s
    float* op = opart + (long)bz * S_LEN * (NHEAD * HDIM);
    #pragma unroll
    for (int dt = 0; dt < 4; ++dt) {
        const int col = h * 64 + dt * 16 + quad * 4;
        float4 v; v.x = oT[dt][0]; v.y = oT[dt][1]; v.z = oT[dt][2]; v.w = oT[dt][3];
        *(float4*)&op[qrow * (NHEAD * HDIM) + col] = v;
    }
    if (l < 16)
        rpart[(long)bz * NHEAD * S_LEN + (long)h * S_LEN + qrow] = total;
}

// ---------------- combine: out = (O0 + O1) / (r0 + r1) ----------------
__global__ __launch_bounds__(256) void combine(
    const float* __restrict__ opart, const float* __restrict__ rpart,
    float* __restrict__ out)
{
    const long idx = (long)blockIdx.x * 256 + threadIdx.x;   // float4 index
    const long row = idx >> 8;                 // 256 float4 per 1024-col row
    const int  c4  = (int)(idx & 255);
    const int  col = c4 * 4;
    const int  h   = col >> 6;

    const float4 a = *(const float4*)&opart[row * 1024 + col];
    const float4 b = *(const float4*)&opart[(long)S_LEN * 1024 + row * 1024 + col];
    const float r  = rpart[(long)h * S_LEN + row] +
                     rpart[(long)NHEAD * S_LEN + (long)h * S_LEN + row];
    const float inv = 1.0f / r;
    float4 o;
    o.x = (a.x + b.x) * inv; o.y = (a.y + b.y) * inv;
    o.z = (a.z + b.z) * inv; o.w = (a.w + b.w) * inv;
    *(float4*)&out[row * 1024 + col] = o;
}

extern "C" void kernel_launch(void* const* d_in, const int* in_sizes, int n_in,
                              void* d_out, int out_size, void* d_ws, size_t ws_size,
                              hipStream_t stream) {
    const float* x  = (const float*)d_in[0];
    const float* wq = (const float*)d_in[1];
    const float* wk = (const float*)d_in[2];
    const float* wv = (const float*)d_in[3];
    float* out = (float*)d_out;

    unsigned short* qkv = (unsigned short*)d_ws;                 // 2048*1280 (Q+K)
    unsigned short* vT  = qkv + (size_t)S_LEN * QKSTR;           // 256*2048  (V^T)
    float* opart = (float*)(vT + (size_t)256 * S_LEN);           // 2*2048*1024 f32
    float* rpart = opart + (size_t)2 * S_LEN * (NHEAD * HDIM);   // 2*16*2048  f32

    proj_gemm<<<dim3(16, 32), dim3(256), 0, stream>>>(x, wq, wk, wv, qkv, vT);
    attn<<<dim3(32, 16, 2), dim3(256), 0, stream>>>(qkv, vT, opart, rpart);
    combine<<<dim3(2048), dim3(256), 0, stream>>>(opart, rpart, out);
}